// Round 2
// baseline (127.098 us; speedup 1.0000x reference)
//
#include <hip/hip_runtime.h>
#include <hip/hip_bf16.h>

typedef __attribute__((ext_vector_type(8))) short short8;
typedef __attribute__((ext_vector_type(4))) float f32x4;

#define NROW 8192
#define DIM 512
#define BHALF 4096
#define NSLICE 8
#define NSLOT (NSLICE * 2)
#define BM 128
#define BN 128
#define BK 32

__device__ __forceinline__ void gload_lds16(const void* g, void* l) {
  __builtin_amdgcn_global_load_lds(
      (const __attribute__((address_space(1))) void*)g,
      (__attribute__((address_space(3))) void*)l,
      16, 0, 0);
}

// ---------------- Kernel 1: row L2-normalize fp32 -> bf16 ----------------
__global__ __launch_bounds__(256) void normalize_kernel(const float* __restrict__ in,
                                                        __hip_bfloat16* __restrict__ out) {
  const int row = blockIdx.x;
  const int t = threadIdx.x;
  const float2 v = ((const float2*)(in + (size_t)row * DIM))[t];
  float ss = v.x * v.x + v.y * v.y;
  #pragma unroll
  for (int m = 1; m < 64; m <<= 1) ss += __shfl_xor(ss, m);
  __shared__ float red[4];
  if ((t & 63) == 0) red[t >> 6] = ss;
  __syncthreads();
  const float tot = red[0] + red[1] + red[2] + red[3];
  const float inv = 1.0f / fmaxf(sqrtf(tot), 1e-12f);
  __hip_bfloat162 pr;
  pr.x = __float2bfloat16(v.x * inv);
  pr.y = __float2bfloat16(v.y * inv);
  ((__hip_bfloat162*)(out + (size_t)row * DIM))[t] = pr;
}

// ---------------- Kernel 2: fused Gram (bf16 MFMA) + per-row exp-sum ----------------
// Grid: (64 row-blocks, NSLICE col-slices). Block = 512 threads = 8 waves (4x2).
// Each block: rows [rb*128, +128), cols [cs*1024, +1024) in 8 tiles of 128.
// Waves w and w^1 share rows (wr) but cover different col halves (wc) -> each
// writes its OWN slot (cs*2 + (w&1)); kernel 3 sums all 16 slots.
__global__ __launch_bounds__(512, 4) void gram_lse_kernel(const __hip_bfloat16* __restrict__ f,
                                                          float* __restrict__ psum,
                                                          float* __restrict__ ppos) {
  __shared__ __align__(16) __hip_bfloat16 lA[BM * BK];
  __shared__ __align__(16) __hip_bfloat16 lB[BN * BK];

  const int tid = threadIdx.x;
  const int lane = tid & 63;
  const int w = tid >> 6;             // wave 0..7
  const int wr = (w >> 1) * 32;       // wave row offset in 128x128 tile
  const int wc = (w & 1) * 64;        // wave col offset
  const int rb = blockIdx.x;
  const int cs = blockIdx.y;
  const int row_base = rb * BM;

  const int fr = lane & 15;           // A-row / B-col within fragment
  const int kq = (lane >> 4) * 8;     // k element offset within BK

  // staging: thread t covers row t>>2 (0..127), k (t&3)*8..+8 (16 bytes)
  const int srow = tid >> 2;
  const int skq = (tid & 3) * 8;
  const __hip_bfloat16* gA_base = f + (size_t)(row_base + srow) * DIM + skq;
  char* ldsA_dst = (char*)lA + w * 1024;   // wave-uniform; HW adds lane*16
  char* ldsB_dst = (char*)lB + w * 1024;

  float rs[2][4];  // per-lane partial exp-sums for rows wr+mi*16+(lane>>4)*4+r
  float ps[2][4];  // positive-pair dot (nonzero on exactly one lane/tile per row)
  #pragma unroll
  for (int mi = 0; mi < 2; ++mi)
    #pragma unroll
    for (int r = 0; r < 4; ++r) { rs[mi][r] = 0.0f; ps[mi][r] = 0.0f; }

  const int tiles = (NROW / NSLICE) / BN;  // 8
  for (int ct = 0; ct < tiles; ++ct) {
    const int col_base = cs * (NROW / NSLICE) + ct * BN;
    const __hip_bfloat16* gB_base = f + (size_t)(col_base + srow) * DIM + skq;

    f32x4 acc[2][4];
    const f32x4 zero = {0.f, 0.f, 0.f, 0.f};
    #pragma unroll
    for (int mi = 0; mi < 2; ++mi)
      #pragma unroll
      for (int nj = 0; nj < 4; ++nj) acc[mi][nj] = zero;

    for (int k0 = 0; k0 < DIM; k0 += BK) {
      __syncthreads();  // previous tile's LDS reads complete
      gload_lds16(gA_base + k0, ldsA_dst);
      gload_lds16(gB_base + k0, ldsB_dst);
      __syncthreads();  // staging complete (compiler drains vmcnt before barrier)

      short8 aF[2], bF[4];
      #pragma unroll
      for (int mi = 0; mi < 2; ++mi)
        aF[mi] = *(const short8*)(lA + (wr + mi * 16 + fr) * BK + kq);
      #pragma unroll
      for (int nj = 0; nj < 4; ++nj)
        bF[nj] = *(const short8*)(lB + (wc + nj * 16 + fr) * BK + kq);
      #pragma unroll
      for (int mi = 0; mi < 2; ++mi)
        #pragma unroll
        for (int nj = 0; nj < 4; ++nj)
          acc[mi][nj] = __builtin_amdgcn_mfma_f32_16x16x32_bf16(aF[mi], bF[nj], acc[mi][nj], 0, 0, 0);
    }

    // epilogue: exp-accumulate; skip diagonal; capture positive pair
    #pragma unroll
    for (int mi = 0; mi < 2; ++mi) {
      const int grow0 = row_base + wr + mi * 16 + ((lane >> 4) << 2);
      #pragma unroll
      for (int nj = 0; nj < 4; ++nj) {
        const int gcol = col_base + wc + nj * 16 + fr;
        #pragma unroll
        for (int r = 0; r < 4; ++r) {
          const float dot = acc[mi][nj][r];
          const float e = __expf((dot - 1.0f) * 10.0f);
          const int grow = grow0 + r;
          rs[mi][r] += (gcol == grow) ? 0.0f : e;
          if (gcol == (grow ^ BHALF)) ps[mi][r] += dot;
        }
      }
    }
  }

  // reduce across the 16 column-lanes (xor over bits 0..3)
  #pragma unroll
  for (int mi = 0; mi < 2; ++mi)
    #pragma unroll
    for (int r = 0; r < 4; ++r) {
      float s = rs[mi][r], p = ps[mi][r];
      #pragma unroll
      for (int m = 1; m < 16; m <<= 1) { s += __shfl_xor(s, m); p += __shfl_xor(p, m); }
      rs[mi][r] = s; ps[mi][r] = p;
    }

  if (fr == 0) {
    const int slot = cs * 2 + (w & 1);   // distinct slot per (slice, col-half)
    #pragma unroll
    for (int mi = 0; mi < 2; ++mi) {
      const int grow0 = row_base + wr + mi * 16 + ((lane >> 4) << 2);
      #pragma unroll
      for (int r = 0; r < 4; ++r) {
        psum[slot * NROW + grow0 + r] = rs[mi][r];
        ppos[slot * NROW + grow0 + r] = ps[mi][r];
      }
    }
  }
}

// ---------------- Kernel 3: combine slots, compute loss ----------------
__global__ __launch_bounds__(256) void loss_reduce_kernel(const float* __restrict__ psum,
                                                          const float* __restrict__ ppos,
                                                          float* __restrict__ out) {
  float local = 0.0f;
  for (int rrow = threadIdx.x; rrow < NROW; rrow += 256) {
    float s = 0.0f, p = 0.0f;
    #pragma unroll
    for (int sl = 0; sl < NSLOT; ++sl) {
      s += psum[sl * NROW + rrow];
      p += ppos[sl * NROW + rrow];
    }
    // LSE = 10 + log(s); loss_row = LSE - p*10
    local += logf(s) + 10.0f - p * 10.0f;
  }
  #pragma unroll
  for (int m = 1; m < 64; m <<= 1) local += __shfl_xor(local, m);
  __shared__ float red[4];
  if ((threadIdx.x & 63) == 0) red[threadIdx.x >> 6] = local;
  __syncthreads();
  if (threadIdx.x == 0)
    out[0] = (red[0] + red[1] + red[2] + red[3]) * (1.0f / (float)BHALF);
}

extern "C" void kernel_launch(void* const* d_in, const int* in_sizes, int n_in,
                              void* d_out, int out_size, void* d_ws, size_t ws_size,
                              hipStream_t stream) {
  const float* feat = (const float*)d_in[0];
  char* ws = (char*)d_ws;
  __hip_bfloat16* f = (__hip_bfloat16*)ws;                         // 8 MB
  float* psum = (float*)(ws + (size_t)NROW * DIM * 2);             // NSLOT*NROW floats
  float* ppos = psum + (size_t)NSLOT * NROW;                       // NSLOT*NROW floats
  float* out = (float*)d_out;

  normalize_kernel<<<NROW, 256, 0, stream>>>(feat, f);
  gram_lse_kernel<<<dim3(NROW / BM, NSLICE), 512, 0, stream>>>(f, psum, ppos);
  loss_reduce_kernel<<<1, 256, 0, stream>>>(psum, ppos, out);
}

// Round 3
// 99.240 us; speedup vs baseline: 1.2807x; 1.2807x over previous
//
#include <hip/hip_runtime.h>
#include <hip/hip_bf16.h>

typedef __attribute__((ext_vector_type(8))) short short8;
typedef __attribute__((ext_vector_type(4))) float f32x4;

#define NROW 8192
#define DIM 512
#define BHALF 4096
#define NB 64            // 128-row blocks
#define BM 128
#define BK 32

__device__ __forceinline__ void gload_lds16(const void* g, void* l) {
  __builtin_amdgcn_global_load_lds(
      (const __attribute__((address_space(1))) void*)g,
      (__attribute__((address_space(3))) void*)l,
      16, 0, 0);
}

// ---------------- Kernel 1: row L2-normalize fp32 -> bf16 ----------------
__global__ __launch_bounds__(256) void normalize_kernel(const float* __restrict__ in,
                                                        __hip_bfloat16* __restrict__ out) {
  const int row = blockIdx.x;
  const int t = threadIdx.x;
  const float2 v = ((const float2*)(in + (size_t)row * DIM))[t];
  float ss = v.x * v.x + v.y * v.y;
  #pragma unroll
  for (int m = 1; m < 64; m <<= 1) ss += __shfl_xor(ss, m);
  __shared__ float red[4];
  if ((t & 63) == 0) red[t >> 6] = ss;
  __syncthreads();
  const float tot = red[0] + red[1] + red[2] + red[3];
  const float inv = 1.0f / fmaxf(sqrtf(tot), 1e-12f);
  __hip_bfloat162 pr;
  pr.x = __float2bfloat16(v.x * inv);
  pr.y = __float2bfloat16(v.y * inv);
  ((__hip_bfloat162*)(out + (size_t)row * DIM))[t] = pr;
}

// ---------------- Kernel 2: symmetric pair-tile Gram + exp-sums ----------------
// 2080 blocks, one per tile-pair (ib<=jb) of 128x128. 256 threads = 4 waves (2x2),
// each wave a 64x64 quadrant (4x4 fragments of 16x16x32) -- m97 structure.
// Off-diag tiles contribute row-sums (rows of ib, slot jb) AND col-sums
// (rows of jb, slot ib). Diagonal tiles: row-sums only (slot ib), diag skipped.
__global__ __launch_bounds__(256) void pair_gram_kernel(const __hip_bfloat16* __restrict__ f,
                                                        float* __restrict__ psum,
                                                        float* __restrict__ ppos) {
  __shared__ __align__(16) __hip_bfloat16 lA[BM * BK];   // 8 KB
  __shared__ __align__(16) __hip_bfloat16 lB[BM * BK];   // 8 KB

  // decode upper-triangle pair (ib <= jb) from blockIdx.x (uniform scalar loop)
  int t = blockIdx.x, ib = 0, base = 0;
  while (base + (NB - ib) <= t) { base += NB - ib; ++ib; }
  const int jb = ib + (t - base);

  const int tid = threadIdx.x;
  const int lane = tid & 63;
  const int w = tid >> 6;            // wave 0..3
  const int wy = w >> 1;             // row half (0/1)
  const int wx = w & 1;              // col half (0/1)
  const int fr = lane & 15;          // fragment row/col index
  const int g = lane >> 4;           // k-group / C-row group
  const int kq = g * 8;              // k element offset in BK

  // staging: thread t covers LDS row t>>2 (0..63 per call), 16B at (t&3)*16
  const int srow = tid >> 2;
  const int skq = (tid & 3) * 8;
  const __hip_bfloat16* gA0 = f + (size_t)(ib * BM + srow) * DIM + skq;
  const __hip_bfloat16* gA1 = gA0 + (size_t)64 * DIM;
  const __hip_bfloat16* gB0 = f + (size_t)(jb * BM + srow) * DIM + skq;
  const __hip_bfloat16* gB1 = gB0 + (size_t)64 * DIM;
  char* dA0 = (char*)lA + w * 1024;  char* dA1 = dA0 + 4096;
  char* dB0 = (char*)lB + w * 1024;  char* dB1 = dB0 + 4096;

  f32x4 acc[4][4];
  const f32x4 zero = {0.f, 0.f, 0.f, 0.f};
  #pragma unroll
  for (int m = 0; m < 4; ++m)
    #pragma unroll
    for (int n = 0; n < 4; ++n) acc[m][n] = zero;

  for (int k0 = 0; k0 < DIM; k0 += BK) {
    __syncthreads();
    gload_lds16(gA0 + k0, dA0);  gload_lds16(gA1 + k0, dA1);
    gload_lds16(gB0 + k0, dB0);  gload_lds16(gB1 + k0, dB1);
    __syncthreads();

    short8 aF[4], bF[4];
    #pragma unroll
    for (int m = 0; m < 4; ++m)
      aF[m] = *(const short8*)(lA + (wy * 64 + m * 16 + fr) * BK + kq);
    #pragma unroll
    for (int n = 0; n < 4; ++n)
      bF[n] = *(const short8*)(lB + (wx * 64 + n * 16 + fr) * BK + kq);
    #pragma unroll
    for (int m = 0; m < 4; ++m)
      #pragma unroll
      for (int n = 0; n < 4; ++n)
        acc[m][n] = __builtin_amdgcn_mfma_f32_16x16x32_bf16(aF[m], bF[n], acc[m][n], 0, 0, 0);
  }

  // ---- epilogue: exp, row-sums + col-sums, positive-pair capture ----
  float rsum[4][4], prow[4][4], csum[4], pcol[4];
  #pragma unroll
  for (int m = 0; m < 4; ++m)
    #pragma unroll
    for (int r = 0; r < 4; ++r) { rsum[m][r] = 0.f; prow[m][r] = 0.f; }
  #pragma unroll
  for (int n = 0; n < 4; ++n) { csum[n] = 0.f; pcol[n] = 0.f; }

  #pragma unroll
  for (int m = 0; m < 4; ++m) {
    #pragma unroll
    for (int n = 0; n < 4; ++n) {
      const int gcol = jb * BM + wx * 64 + n * 16 + fr;
      #pragma unroll
      for (int r = 0; r < 4; ++r) {
        const int grow = ib * BM + wy * 64 + m * 16 + g * 4 + r;
        const float dot = acc[m][n][r];
        const float e = (gcol == grow) ? 0.f : __expf((dot - 1.0f) * 10.0f);
        const float pos = (gcol == (grow ^ BHALF)) ? dot : 0.f;
        rsum[m][r] += e;   prow[m][r] += pos;
        csum[n]    += e;   pcol[n]    += pos;
      }
    }
  }

  // row side: reduce over fr (lane bits 0..3)
  #pragma unroll
  for (int m = 0; m < 4; ++m)
    #pragma unroll
    for (int r = 0; r < 4; ++r) {
      float a = rsum[m][r], b = prow[m][r];
      #pragma unroll
      for (int msk = 1; msk < 16; msk <<= 1) { a += __shfl_xor(a, msk); b += __shfl_xor(b, msk); }
      rsum[m][r] = a; prow[m][r] = b;
    }
  // col side: reduce over g (lane bits 4..5)
  #pragma unroll
  for (int n = 0; n < 4; ++n) {
    float a = csum[n], b = pcol[n];
    a += __shfl_xor(a, 16); b += __shfl_xor(b, 16);
    a += __shfl_xor(a, 32); b += __shfl_xor(b, 32);
    csum[n] = a; pcol[n] = b;
  }

  // cross-wave combine via LDS (alias over lA; all K-loop reads done after barrier)
  __syncthreads();
  float* sred = (float*)lA;   // [0,256): sr[wx][row]  [256,512): spr[wx][row]
                              // [512,768): sc[wy][col] [768,1024): spc[wy][col]
  if (fr == 0) {
    #pragma unroll
    for (int m = 0; m < 4; ++m)
      #pragma unroll
      for (int r = 0; r < 4; ++r) {
        const int row = wy * 64 + m * 16 + g * 4 + r;
        sred[wx * 128 + row]       = rsum[m][r];
        sred[256 + wx * 128 + row] = prow[m][r];
      }
  }
  if (g == 0) {
    #pragma unroll
    for (int n = 0; n < 4; ++n) {
      const int col = wx * 64 + n * 16 + fr;
      sred[512 + wy * 128 + col] = csum[n];
      sred[768 + wy * 128 + col] = pcol[n];
    }
  }
  __syncthreads();

  if (tid < 128) {                       // rows of block ib -> slot jb
    const int row = tid;
    const float s = sred[row] + sred[128 + row];
    const float p = sred[256 + row] + sred[384 + row];
    psum[(size_t)jb * NROW + ib * BM + row] = s;
    ppos[(size_t)jb * NROW + ib * BM + row] = p;
  } else if (ib != jb) {                 // rows of block jb -> slot ib (transpose side)
    const int col = tid - 128;
    const float s = sred[512 + col] + sred[640 + col];
    const float p = sred[768 + col] + sred[896 + col];
    psum[(size_t)ib * NROW + jb * BM + col] = s;
    ppos[(size_t)ib * NROW + jb * BM + col] = p;
  }
}

// ---------------- Kernel 3a: per-row loss, 64 partials ----------------
__global__ __launch_bounds__(128) void loss_stage1(const float* __restrict__ psum,
                                                   const float* __restrict__ ppos,
                                                   float* __restrict__ partial) {
  const int row = blockIdx.x * 128 + threadIdx.x;
  float s = 0.f, p = 0.f;
  #pragma unroll 8
  for (int sl = 0; sl < NB; ++sl) {
    s += psum[(size_t)sl * NROW + row];
    p += ppos[(size_t)sl * NROW + row];
  }
  float local = logf(s) + 10.0f - 10.0f * p;
  #pragma unroll
  for (int m = 1; m < 64; m <<= 1) local += __shfl_xor(local, m);
  __shared__ float red[2];
  if ((threadIdx.x & 63) == 0) red[threadIdx.x >> 6] = local;
  __syncthreads();
  if (threadIdx.x == 0) partial[blockIdx.x] = red[0] + red[1];
}

// ---------------- Kernel 3b: final scalar ----------------
__global__ __launch_bounds__(64) void loss_stage2(const float* __restrict__ partial,
                                                  float* __restrict__ out) {
  float v = partial[threadIdx.x];
  #pragma unroll
  for (int m = 1; m < 64; m <<= 1) v += __shfl_xor(v, m);
  if (threadIdx.x == 0) out[0] = v * (1.0f / (float)BHALF);
}

extern "C" void kernel_launch(void* const* d_in, const int* in_sizes, int n_in,
                              void* d_out, int out_size, void* d_ws, size_t ws_size,
                              hipStream_t stream) {
  const float* feat = (const float*)d_in[0];
  char* ws = (char*)d_ws;
  __hip_bfloat16* f = (__hip_bfloat16*)ws;                         // 8 MB
  float* psum = (float*)(ws + (size_t)NROW * DIM * 2);             // NB*NROW floats (2 MB)
  float* ppos = psum + (size_t)NB * NROW;                          // 2 MB
  float* partial = ppos + (size_t)NB * NROW;                       // 64 floats
  float* out = (float*)d_out;

  normalize_kernel<<<NROW, 256, 0, stream>>>(feat, f);
  const int npairs = NB * (NB + 1) / 2;                            // 2080
  pair_gram_kernel<<<npairs, 256, 0, stream>>>(f, psum, ppos);
  loss_stage1<<<NB, 128, 0, stream>>>(psum, ppos, partial);
  loss_stage2<<<1, 64, 0, stream>>>(partial, out);
}

// Round 4
// 93.806 us; speedup vs baseline: 1.3549x; 1.0579x over previous
//
#include <hip/hip_runtime.h>
#include <hip/hip_bf16.h>

typedef __attribute__((ext_vector_type(8))) short short8;
typedef __attribute__((ext_vector_type(4))) float f32x4;

#define NROW 8192
#define DIM 512
#define BHALF 4096
#define NB 64            // number of 128-row blocks
#define BM 128
#define BK 32
#define NPAIR 2080       // NB*(NB+1)/2
#define XCHUNK (NPAIR / 8)

__device__ __forceinline__ void gload_lds16(const void* g, void* l) {
  __builtin_amdgcn_global_load_lds(
      (const __attribute__((address_space(1))) void*)g,
      (__attribute__((address_space(3))) void*)l,
      16, 0, 0);
}

// ---------------- Kernel 1: row L2-normalize fp32 -> bf16 (wave per row) ----------------
__global__ __launch_bounds__(256) void normalize_kernel(const float* __restrict__ in,
                                                        __hip_bfloat16* __restrict__ out) {
  const int w = threadIdx.x >> 6, lane = threadIdx.x & 63;
  const int row = blockIdx.x * 4 + w;
  const float4* src = (const float4*)(in + (size_t)row * DIM) + lane * 2;
  const float4 v0 = src[0], v1 = src[1];
  float ss = v0.x * v0.x + v0.y * v0.y + v0.z * v0.z + v0.w * v0.w
           + v1.x * v1.x + v1.y * v1.y + v1.z * v1.z + v1.w * v1.w;
  #pragma unroll
  for (int m = 1; m < 64; m <<= 1) ss += __shfl_xor(ss, m);
  const float inv = 1.0f / fmaxf(sqrtf(ss), 1e-12f);
  __hip_bfloat16 o[8];
  o[0] = __float2bfloat16(v0.x * inv); o[1] = __float2bfloat16(v0.y * inv);
  o[2] = __float2bfloat16(v0.z * inv); o[3] = __float2bfloat16(v0.w * inv);
  o[4] = __float2bfloat16(v1.x * inv); o[5] = __float2bfloat16(v1.y * inv);
  o[6] = __float2bfloat16(v1.z * inv); o[7] = __float2bfloat16(v1.w * inv);
  *(short8*)(out + (size_t)row * DIM + lane * 8) = *(const short8*)o;
}

// ---------------- Kernel 2: symmetric pair-tile Gram + exp-sums ----------------
// 2080 blocks, one per (ib<=jb) 128x128 tile-pair. 256 threads = 4 waves (2x2),
// 4x4 fragments each (m97 structure). Double-buffered LDS, 2-phase pipeline:
// issue next K-tile's global_load_lds BEFORE current tile's ds_read+MFMA.
// Pair order: 16x16 macro-tiles (4MB panel working set = per-XCD L2) + bijective
// XCD swizzle so each XCD walks a contiguous macro-ordered chunk.
__global__ __launch_bounds__(256) void pair_gram_kernel(const __hip_bfloat16* __restrict__ f,
                                                        float* __restrict__ psum,
                                                        float* __restrict__ ppos) {
  __shared__ __align__(16) __hip_bfloat16 lA[2][BM * BK];   // 2 x 8 KB
  __shared__ __align__(16) __hip_bfloat16 lB[2][BM * BK];   // 2 x 8 KB

  // --- XCD swizzle + macro-tiled pair decode (all scalar-uniform) ---
  const int bid = blockIdx.x;
  const int wg = (bid & 7) * XCHUNK + (bid >> 3);
  int rem = wg, MI = 0, MJ = 0;
  {
    bool brk = false;
    for (MI = 0; MI < 4 && !brk; ++MI) {
      for (MJ = MI; MJ < 4; ++MJ) {
        const int sz = (MI == MJ) ? 136 : 256;
        if (rem < sz) { brk = true; break; }
        rem -= sz;
      }
    }
    if (brk) --MI;  // undo final ++ from the for-loop
  }
  int ib, jb;
  if (MI == MJ) {
    int i = 0, b = 0;
    while (b + (16 - i) <= rem) { b += 16 - i; ++i; }
    ib = MI * 16 + i; jb = MI * 16 + i + (rem - b);
  } else {
    ib = MI * 16 + (rem >> 4); jb = MJ * 16 + (rem & 15);
  }

  const int tid = threadIdx.x;
  const int lane = tid & 63;
  const int w = tid >> 6;            // wave 0..3
  const int wy = w >> 1;             // row half (0/1)
  const int wx = w & 1;              // col half (0/1)
  const int fr = lane & 15;          // fragment row/col index
  const int g = lane >> 4;           // k-group / C-row group
  const int kq = g * 8;              // k element offset in BK

  // staging: thread t covers LDS row t>>2 (0..63 per call), 16B at (t&3)*16
  const int srow = tid >> 2;
  const int skq = (tid & 3) * 8;
  const __hip_bfloat16* gA = f + (size_t)(ib * BM + srow) * DIM + skq;
  const __hip_bfloat16* gB = f + (size_t)(jb * BM + srow) * DIM + skq;

  f32x4 acc[4][4];
  const f32x4 zero = {0.f, 0.f, 0.f, 0.f};
  #pragma unroll
  for (int m = 0; m < 4; ++m)
    #pragma unroll
    for (int n = 0; n < 4; ++n) acc[m][n] = zero;

  // prologue: stage K-tile 0 into buffer 0
  {
    char* dA = (char*)lA[0] + w * 1024;
    char* dB = (char*)lB[0] + w * 1024;
    gload_lds16(gA, dA);  gload_lds16(gA + (size_t)64 * DIM, dA + 4096);
    gload_lds16(gB, dB);  gload_lds16(gB + (size_t)64 * DIM, dB + 4096);
  }
  __syncthreads();   // drains vmcnt: buffer 0 ready

  int cur = 0;
  for (int t = 0; t < 16; ++t) {
    // issue next tile's loads (hidden under this tile's ds_read+MFMA)
    if (t < 15) {
      const int kn = (t + 1) * BK;
      char* dA = (char*)lA[cur ^ 1] + w * 1024;
      char* dB = (char*)lB[cur ^ 1] + w * 1024;
      gload_lds16(gA + kn, dA);  gload_lds16(gA + (size_t)64 * DIM + kn, dA + 4096);
      gload_lds16(gB + kn, dB);  gload_lds16(gB + (size_t)64 * DIM + kn, dB + 4096);
    }

    const __hip_bfloat16* pA = lA[cur];
    const __hip_bfloat16* pB = lB[cur];
    short8 aF[4], bF[4];
    #pragma unroll
    for (int m = 0; m < 4; ++m)
      aF[m] = *(const short8*)(pA + (wy * 64 + m * 16 + fr) * BK + kq);
    #pragma unroll
    for (int n = 0; n < 4; ++n)
      bF[n] = *(const short8*)(pB + (wx * 64 + n * 16 + fr) * BK + kq);
    #pragma unroll
    for (int m = 0; m < 4; ++m)
      #pragma unroll
      for (int n = 0; n < 4; ++n)
        acc[m][n] = __builtin_amdgcn_mfma_f32_16x16x32_bf16(aF[m], bF[n], acc[m][n], 0, 0, 0);

    __syncthreads();   // drains vmcnt (next buffer staged) + lgkm; all reads done
    cur ^= 1;
  }

  // ---- epilogue: exp, row-sums + col-sums, positive-pair capture ----
  float rsum[4][4], prow[4][4], csum[4], pcol[4];
  #pragma unroll
  for (int m = 0; m < 4; ++m)
    #pragma unroll
    for (int r = 0; r < 4; ++r) { rsum[m][r] = 0.f; prow[m][r] = 0.f; }
  #pragma unroll
  for (int n = 0; n < 4; ++n) { csum[n] = 0.f; pcol[n] = 0.f; }

  #pragma unroll
  for (int m = 0; m < 4; ++m) {
    #pragma unroll
    for (int n = 0; n < 4; ++n) {
      const int gcol = jb * BM + wx * 64 + n * 16 + fr;
      #pragma unroll
      for (int r = 0; r < 4; ++r) {
        const int grow = ib * BM + wy * 64 + m * 16 + g * 4 + r;
        const float dot = acc[m][n][r];
        const float e = (gcol == grow) ? 0.f : __expf((dot - 1.0f) * 10.0f);
        const float pos = (gcol == (grow ^ BHALF)) ? dot : 0.f;
        rsum[m][r] += e;   prow[m][r] += pos;
        csum[n]    += e;   pcol[n]    += pos;
      }
    }
  }

  // row side: reduce over fr (lane bits 0..3)
  #pragma unroll
  for (int m = 0; m < 4; ++m)
    #pragma unroll
    for (int r = 0; r < 4; ++r) {
      float a = rsum[m][r], b = prow[m][r];
      #pragma unroll
      for (int msk = 1; msk < 16; msk <<= 1) { a += __shfl_xor(a, msk); b += __shfl_xor(b, msk); }
      rsum[m][r] = a; prow[m][r] = b;
    }
  // col side: reduce over g (lane bits 4..5)
  #pragma unroll
  for (int n = 0; n < 4; ++n) {
    float a = csum[n], b = pcol[n];
    a += __shfl_xor(a, 16); b += __shfl_xor(b, 16);
    a += __shfl_xor(a, 32); b += __shfl_xor(b, 32);
    csum[n] = a; pcol[n] = b;
  }

  // cross-wave combine via LDS (alias over lA; all K-loop reads done)
  __syncthreads();
  float* sred = (float*)lA;   // [0,256): sr[wx][row]  [256,512): spr[wx][row]
                              // [512,768): sc[wy][col] [768,1024): spc[wy][col]
  if (fr == 0) {
    #pragma unroll
    for (int m = 0; m < 4; ++m)
      #pragma unroll
      for (int r = 0; r < 4; ++r) {
        const int row = wy * 64 + m * 16 + g * 4 + r;
        sred[wx * 128 + row]       = rsum[m][r];
        sred[256 + wx * 128 + row] = prow[m][r];
      }
  }
  if (g == 0) {
    #pragma unroll
    for (int n = 0; n < 4; ++n) {
      const int col = wx * 64 + n * 16 + fr;
      sred[512 + wy * 128 + col] = csum[n];
      sred[768 + wy * 128 + col] = pcol[n];
    }
  }
  __syncthreads();

  if (tid < 128) {                       // rows of block ib -> slot jb
    const int row = tid;
    const float s = sred[row] + sred[128 + row];
    const float p = sred[256 + row] + sred[384 + row];
    psum[(size_t)jb * NROW + ib * BM + row] = s;
    ppos[(size_t)jb * NROW + ib * BM + row] = p;
  } else if (ib != jb) {                 // rows of block jb -> slot ib (transpose side)
    const int col = tid - 128;
    const float s = sred[512 + col] + sred[640 + col];
    const float p = sred[768 + col] + sred[896 + col];
    psum[(size_t)ib * NROW + jb * BM + col] = s;
    ppos[(size_t)ib * NROW + jb * BM + col] = p;
  }
}

// ---------------- Kernel 3a: per-row loss, 64 partials ----------------
__global__ __launch_bounds__(128) void loss_stage1(const float* __restrict__ psum,
                                                   const float* __restrict__ ppos,
                                                   float* __restrict__ partial) {
  const int row = blockIdx.x * 128 + threadIdx.x;
  float s = 0.f, p = 0.f;
  #pragma unroll 8
  for (int sl = 0; sl < NB; ++sl) {
    s += psum[(size_t)sl * NROW + row];
    p += ppos[(size_t)sl * NROW + row];
  }
  float local = logf(s) + 10.0f - 10.0f * p;
  #pragma unroll
  for (int m = 1; m < 64; m <<= 1) local += __shfl_xor(local, m);
  __shared__ float red[2];
  if ((threadIdx.x & 63) == 0) red[threadIdx.x >> 6] = local;
  __syncthreads();
  if (threadIdx.x == 0) partial[blockIdx.x] = red[0] + red[1];
}

// ---------------- Kernel 3b: final scalar ----------------
__global__ __launch_bounds__(64) void loss_stage2(const float* __restrict__ partial,
                                                  float* __restrict__ out) {
  float v = partial[threadIdx.x];
  #pragma unroll
  for (int m = 1; m < 64; m <<= 1) v += __shfl_xor(v, m);
  if (threadIdx.x == 0) out[0] = v * (1.0f / (float)BHALF);
}

extern "C" void kernel_launch(void* const* d_in, const int* in_sizes, int n_in,
                              void* d_out, int out_size, void* d_ws, size_t ws_size,
                              hipStream_t stream) {
  const float* feat = (const float*)d_in[0];
  char* ws = (char*)d_ws;
  __hip_bfloat16* f = (__hip_bfloat16*)ws;                         // 8 MB
  float* psum = (float*)(ws + (size_t)NROW * DIM * 2);             // 2 MB
  float* ppos = psum + (size_t)NB * NROW;                          // 2 MB
  float* partial = ppos + (size_t)NB * NROW;                       // 64 floats
  float* out = (float*)d_out;

  normalize_kernel<<<NROW / 4, 256, 0, stream>>>(feat, f);
  pair_gram_kernel<<<NPAIR, 256, 0, stream>>>(f, psum, ppos);
  loss_stage1<<<NB, 128, 0, stream>>>(psum, ppos, partial);
  loss_stage2<<<1, 64, 0, stream>>>(partial, out);
}

// Round 5
// 82.298 us; speedup vs baseline: 1.5444x; 1.1398x over previous
//
#include <hip/hip_runtime.h>
#include <hip/hip_bf16.h>

typedef __attribute__((ext_vector_type(8))) short short8;
typedef __attribute__((ext_vector_type(4))) float f32x4;

#define NROW 8192
#define DIM 512
#define BHALF 4096
#define NB2 32           // number of 256-row blocks
#define BT 256           // tile size
#define BK 64
#define NPAIR2 528       // NB2*(NB2+1)/2
#define XCHUNK2 66       // 528/8

__device__ __forceinline__ void gload_lds16(const void* g, void* l) {
  __builtin_amdgcn_global_load_lds(
      (const __attribute__((address_space(1))) void*)g,
      (__attribute__((address_space(3))) void*)l,
      16, 0, 0);
}

// ---------------- Kernel 1: row L2-normalize fp32 -> bf16 (wave per row) ----------------
__global__ __launch_bounds__(256) void normalize_kernel(const float* __restrict__ in,
                                                        __hip_bfloat16* __restrict__ out) {
  const int w = threadIdx.x >> 6, lane = threadIdx.x & 63;
  const int row = blockIdx.x * 4 + w;
  const float4* src = (const float4*)(in + (size_t)row * DIM) + lane * 2;
  const float4 v0 = src[0], v1 = src[1];
  float ss = v0.x * v0.x + v0.y * v0.y + v0.z * v0.z + v0.w * v0.w
           + v1.x * v1.x + v1.y * v1.y + v1.z * v1.z + v1.w * v1.w;
  #pragma unroll
  for (int m = 1; m < 64; m <<= 1) ss += __shfl_xor(ss, m);
  const float inv = 1.0f / fmaxf(sqrtf(ss), 1e-12f);
  __hip_bfloat16 o[8];
  o[0] = __float2bfloat16(v0.x * inv); o[1] = __float2bfloat16(v0.y * inv);
  o[2] = __float2bfloat16(v0.z * inv); o[3] = __float2bfloat16(v0.w * inv);
  o[4] = __float2bfloat16(v1.x * inv); o[5] = __float2bfloat16(v1.y * inv);
  o[6] = __float2bfloat16(v1.z * inv); o[7] = __float2bfloat16(v1.w * inv);
  *(short8*)(out + (size_t)row * DIM + lane * 8) = *(const short8*)o;
}

// ---------------- Kernel 2: symmetric 256x256 pair-tile Gram + exp-sums ----------------
// 528 blocks, one per (ib<=jb) pair of 256-row blocks. 512 threads = 8 waves
// (2 row-halves x 4 col-quarters); per-wave output 128x64 = 8x4 frags of 16x16.
// BK=64, double-buffered 128KB LDS, 2-phase pipeline (stage t+1 before compute t).
// T2 XOR-swizzle (T21-correct): linear gload_lds dest + inverse-permuted global
// source + XOR'd ds_read. LDS slot (row, s) holds global col16 s^(row&7).
__global__ __launch_bounds__(512, 2) void pair_gram_kernel(const __hip_bfloat16* __restrict__ f,
                                                           float* __restrict__ psum,
                                                           float* __restrict__ ppos) {
  __shared__ __align__(16) __hip_bfloat16 lds[2][2][BT * BK];   // [buf][A/B][256*64] = 128KB

  // --- XCD swizzle + 8x8 macro-tiled triangular pair decode (scalar-uniform) ---
  const int bid = blockIdx.x;
  const int wg = (bid & 7) * XCHUNK2 + (bid >> 3);
  int rem = wg, MI = 0, MJ = 0;
  {
    bool brk = false;
    for (MI = 0; MI < 4 && !brk; ++MI) {
      for (MJ = MI; MJ < 4; ++MJ) {
        const int sz = (MI == MJ) ? 36 : 64;
        if (rem < sz) { brk = true; break; }
        rem -= sz;
      }
    }
    if (brk) --MI;
  }
  int ib, jb;
  if (MI == MJ) {          // 8x8 triangle: 36 entries
    int i = 0, b = 0;
    while (b + (8 - i) <= rem) { b += 8 - i; ++i; }
    ib = MI * 8 + i; jb = MI * 8 + i + (rem - b);
  } else {
    ib = MI * 8 + (rem >> 3); jb = MJ * 8 + (rem & 7);
  }

  const int tid = threadIdx.x;
  const int lane = tid & 63;
  const int w = tid >> 6;            // wave 0..7
  const int wm = w >> 2;             // row half (0/1): rows wm*128..+128
  const int wn = w & 3;              // col quarter: cols wn*64..+64
  const int fr = lane & 15;          // fragment row/col index
  const int g = lane >> 4;           // k-group / C-row group

  // staging source (inverse-swizzled): lane l covers row w*8+(l>>3), col16 (l&7)^((l>>3)&7)
  const int srow8 = lane >> 3;
  const int scol = (lane & 7) ^ srow8;
  const __hip_bfloat16* gA = f + (size_t)(ib * BT + w * 8 + srow8) * DIM + scol * 8;
  const __hip_bfloat16* gB = f + (size_t)(jb * BT + w * 8 + srow8) * DIM + scol * 8;

  f32x4 acc[8][4];
  const f32x4 zero = {0.f, 0.f, 0.f, 0.f};
  #pragma unroll
  for (int mi = 0; mi < 8; ++mi)
    #pragma unroll
    for (int ni = 0; ni < 4; ++ni) acc[mi][ni] = zero;

  // read-side swizzled k-offsets (row&7 == fr&7 for every fragment row)
  const int sk0 = ((0 * 4 + g) ^ (fr & 7)) * 16;   // kk=0 byte offset within row
  const int sk1 = ((1 * 4 + g) ^ (fr & 7)) * 16;   // kk=1

  #define STAGE(buf, k0)                                                        \
    {                                                                           \
      char* dA = (char*)&lds[buf][0][0] + w * 1024;                             \
      char* dB = (char*)&lds[buf][1][0] + w * 1024;                             \
      _Pragma("unroll")                                                         \
      for (int q = 0; q < 4; ++q) {                                             \
        gload_lds16(gA + (k0) + (size_t)q * 64 * DIM, dA + q * 8192);           \
        gload_lds16(gB + (k0) + (size_t)q * 64 * DIM, dB + q * 8192);           \
      }                                                                         \
    }

  STAGE(0, 0);
  __syncthreads();   // buffer 0 ready

  for (int t = 0; t < 8; ++t) {
    const int cur = t & 1;
    if (t < 7) STAGE(cur ^ 1, (t + 1) * BK);   // hidden under this tile's compute

    const char* pA = (const char*)&lds[cur][0][0];
    const char* pB = (const char*)&lds[cur][1][0];
    #pragma unroll
    for (int kk = 0; kk < 2; ++kk) {
      const int sk = kk ? sk1 : sk0;
      short8 aF[8], bF[4];
      #pragma unroll
      for (int mi = 0; mi < 8; ++mi)
        aF[mi] = *(const short8*)(pA + (wm * 128 + mi * 16 + fr) * 128 + sk);
      #pragma unroll
      for (int ni = 0; ni < 4; ++ni)
        bF[ni] = *(const short8*)(pB + (wn * 64 + ni * 16 + fr) * 128 + sk);
      #pragma unroll
      for (int mi = 0; mi < 8; ++mi)
        #pragma unroll
        for (int ni = 0; ni < 4; ++ni)
          acc[mi][ni] = __builtin_amdgcn_mfma_f32_16x16x32_bf16(aF[mi], bF[ni], acc[mi][ni], 0, 0, 0);
    }
    __syncthreads();   // staging of next buffer complete; all reads of cur done
  }
  #undef STAGE

  // ---- epilogue: exp, row-sums (rows of ib) + col-sums (rows of jb), pos-pair ----
  // LDS scratch (aliases lds[0], safe after final barrier):
  //   rS[wn][256] @0, rP[wn][256] @1024, cS[wm][256] @2048, cP[wm][256] @2560 (floats)
  float* sc = (float*)&lds[0][0][0];
  float csum[4] = {0.f, 0.f, 0.f, 0.f}, pcol[4] = {0.f, 0.f, 0.f, 0.f};

  #pragma unroll
  for (int mi = 0; mi < 8; ++mi) {
    float rs4[4] = {0.f, 0.f, 0.f, 0.f}, pp4[4] = {0.f, 0.f, 0.f, 0.f};
    #pragma unroll
    for (int ni = 0; ni < 4; ++ni) {
      const int gcol = jb * BT + wn * 64 + ni * 16 + fr;
      #pragma unroll
      for (int r = 0; r < 4; ++r) {
        const int grow = ib * BT + wm * 128 + mi * 16 + g * 4 + r;
        const float dot = acc[mi][ni][r];
        const float e = (gcol == grow) ? 0.f : __expf((dot - 1.0f) * 10.0f);
        const float pos = (gcol == (grow ^ BHALF)) ? dot : 0.f;
        rs4[r] += e;  pp4[r] += pos;
        csum[ni] += e;  pcol[ni] += pos;
      }
    }
    #pragma unroll
    for (int r = 0; r < 4; ++r) {
      float a = rs4[r], b = pp4[r];
      #pragma unroll
      for (int msk = 1; msk < 16; msk <<= 1) { a += __shfl_xor(a, msk); b += __shfl_xor(b, msk); }
      rs4[r] = a; pp4[r] = b;
    }
    if (fr == 0) {
      #pragma unroll
      for (int r = 0; r < 4; ++r) {
        const int row = wm * 128 + mi * 16 + g * 4 + r;
        sc[wn * 256 + row]        = rs4[r];
        sc[1024 + wn * 256 + row] = pp4[r];
      }
    }
  }
  #pragma unroll
  for (int ni = 0; ni < 4; ++ni) {
    float a = csum[ni], b = pcol[ni];
    a += __shfl_xor(a, 16); b += __shfl_xor(b, 16);
    a += __shfl_xor(a, 32); b += __shfl_xor(b, 32);
    if (g == 0) {
      const int col = wn * 64 + ni * 16 + fr;
      sc[2048 + wm * 256 + col] = a;
      sc[2560 + wm * 256 + col] = b;
    }
  }
  __syncthreads();

  if (tid < 256) {                     // rows of block ib -> slot jb
    const int row = tid;
    const float s = sc[row] + sc[256 + row] + sc[512 + row] + sc[768 + row];
    const float p = sc[1024 + row] + sc[1280 + row] + sc[1536 + row] + sc[1792 + row];
    psum[(size_t)jb * NROW + ib * BT + row] = s;
    ppos[(size_t)jb * NROW + ib * BT + row] = p;
  } else if (ib != jb) {               // rows of block jb -> slot ib (transpose side)
    const int col = tid - 256;
    const float s = sc[2048 + col] + sc[2304 + col];
    const float p = sc[2560 + col] + sc[2816 + col];
    psum[(size_t)ib * NROW + jb * BT + col] = s;
    ppos[(size_t)ib * NROW + jb * BT + col] = p;
  }
}

// ---------------- Kernel 3a: per-row loss, 64 partials ----------------
__global__ __launch_bounds__(128) void loss_stage1(const float* __restrict__ psum,
                                                   const float* __restrict__ ppos,
                                                   float* __restrict__ partial) {
  const int row = blockIdx.x * 128 + threadIdx.x;
  float s = 0.f, p = 0.f;
  #pragma unroll 8
  for (int sl = 0; sl < NB2; ++sl) {
    s += psum[(size_t)sl * NROW + row];
    p += ppos[(size_t)sl * NROW + row];
  }
  float local = logf(s) + 10.0f - 10.0f * p;
  #pragma unroll
  for (int m = 1; m < 64; m <<= 1) local += __shfl_xor(local, m);
  __shared__ float red[2];
  if ((threadIdx.x & 63) == 0) red[threadIdx.x >> 6] = local;
  __syncthreads();
  if (threadIdx.x == 0) partial[blockIdx.x] = red[0] + red[1];
}

// ---------------- Kernel 3b: final scalar ----------------
__global__ __launch_bounds__(64) void loss_stage2(const float* __restrict__ partial,
                                                  float* __restrict__ out) {
  float v = partial[threadIdx.x];
  #pragma unroll
  for (int m = 1; m < 64; m <<= 1) v += __shfl_xor(v, m);
  if (threadIdx.x == 0) out[0] = v * (1.0f / (float)BHALF);
}

extern "C" void kernel_launch(void* const* d_in, const int* in_sizes, int n_in,
                              void* d_out, int out_size, void* d_ws, size_t ws_size,
                              hipStream_t stream) {
  const float* feat = (const float*)d_in[0];
  char* ws = (char*)d_ws;
  __hip_bfloat16* f = (__hip_bfloat16*)ws;                         // 8 MB
  float* psum = (float*)(ws + (size_t)NROW * DIM * 2);             // NB2*NROW floats (1 MB)
  float* ppos = psum + (size_t)NB2 * NROW;                         // 1 MB
  float* partial = ppos + (size_t)NB2 * NROW;                      // 64 floats
  float* out = (float*)d_out;

  normalize_kernel<<<NROW / 4, 256, 0, stream>>>(feat, f);
  pair_gram_kernel<<<NPAIR2, 512, 0, stream>>>(f, psum, ppos);
  loss_stage1<<<NROW / 128, 128, 0, stream>>>(psum, ppos, partial);
  loss_stage2<<<1, 64, 0, stream>>>(partial, out);
}